// Round 1
// baseline (188.215 us; speedup 1.0000x reference)
//
#include <hip/hip_runtime.h>
#include <math.h>

#define B_ 32
#define N_ 2048
#define M_ 16
#define K_ 32
#define EPS 1e-12f

constexpr int CHUNKS = 16;
constexpr int NC = N_ / CHUNKS;   // 128 rows per block
constexpr int THREADS = 256;      // 8 n-groups x 32 k

// ---------------- kernel 1: find first invalid n per batch ----------------
__global__ void scan_valid_kernel(const float* __restrict__ dgm,
                                  unsigned* __restrict__ finv) {
    int idx = blockIdx.x * blockDim.x + threadIdx.x;   // 0 .. B*N-1
    if (idx >= B_ * N_) return;
    int b = idx >> 11;            // N_ = 2048
    int n = idx & (N_ - 1);
    const float* row = dgm + (size_t)idx * (M_ + 1);
    float h = row[0];
    bool any_nz = false;
#pragma unroll
    for (int j = 0; j < M_ + 1; ++j) any_nz |= (row[j] != 0.0f);
    bool ok = ((int)h <= 1) && any_nz;
    if (!ok) atomicMin(&finv[b], (unsigned)n);
}

// ---------------- kernel 2: main accumulation ----------------
// G[b,k,m] = sum_n w[b,n] * coef[b,n,k] * y[b,n,m]
__global__ __launch_bounds__(THREADS) void pml_main_kernel(
    const float* __restrict__ dgm, const float* __restrict__ theta,
    const float* __restrict__ class_w, const unsigned* __restrict__ finv,
    float* __restrict__ G)
{
    __shared__ __align__(16) float y_lds[NC * M_];   // 8 KB
    __shared__ float hom_lds[NC];
    __shared__ float w_lds[NC];
    __shared__ float red[8 * K_ * M_];               // 16 KB

    const int b  = blockIdx.y;
    const int n0 = blockIdx.x * NC;
    const unsigned fi = finv[b];
    if ((unsigned)n0 >= fi) return;   // whole chunk invalid -> contributes 0

    const int tid = threadIdx.x;

    // stage dgm chunk into LDS, splitting hom / y
    const float* src = dgm + ((size_t)b * N_ + n0) * (M_ + 1);
    for (int i = tid; i < NC * (M_ + 1); i += THREADS) {
        float v = src[i];
        int nl = i / (M_ + 1);
        int j  = i - nl * (M_ + 1);
        if (j == 0) hom_lds[nl] = v;
        else        y_lds[nl * M_ + (j - 1)] = v;
    }
    __syncthreads();

    const float cw0 = class_w[0], cw1 = class_w[1];
    for (int nl = tid; nl < NC; nl += THREADS) {
        unsigned n = (unsigned)(n0 + nl);
        float w = 0.0f;
        if (n < fi) {
            int h = (int)hom_lds[nl];
            h = min(max(h, 0), 1);
            w = h ? cw1 : cw0;
        }
        w_lds[nl] = w;
    }
    __syncthreads();

    const int k   = tid & (K_ - 1);
    const int grp = tid >> 5;         // 0..7

    float t2[M_];
#pragma unroll
    for (int m = 0; m < M_; ++m) { float t = theta[k * M_ + m]; t2[m] = t * t; }

    float g[M_];
#pragma unroll
    for (int m = 0; m < M_; ++m) g[m] = 0.0f;

    const int nl_end = (int)min((unsigned)NC, fi - (unsigned)n0);

    for (int nl = grp; nl < nl_end; nl += 8) {
        float w = w_lds[nl];
        const float4* yv = (const float4*)(y_lds + nl * M_);
        float4 v0 = yv[0], v1 = yv[1], v2 = yv[2], v3 = yv[3];
        float y[M_] = { v0.x, v0.y, v0.z, v0.w,  v1.x, v1.y, v1.z, v1.w,
                        v2.x, v2.y, v2.z, v2.w,  v3.x, v3.y, v3.z, v3.w };
        float s = 0.0f;
#pragma unroll
        for (int m = 0; m < M_; ++m) s = fmaf(y[m] * y[m], t2[m], s);
        // d = 1 + sqrt(1 + un^2), un^2 = s + EPS
        float d  = 1.0f + sqrtf(1.0f + s + EPS);
        float xn = sqrtf(s / (d * d) + EPS);
        float xc = fminf(xn, 1.0f - 1e-5f);
        float coef = atanhf(xc) / (xn * d);
        float wc = w * coef;
#pragma unroll
        for (int m = 0; m < M_; ++m) g[m] = fmaf(wc, y[m], g[m]);
    }

    // block reduction over the 8 n-groups
    float* myred = red + (grp * K_ + k) * M_;
#pragma unroll
    for (int m = 0; m < M_; ++m) myred[m] = g[m];
    __syncthreads();

    float* Gb = G + (size_t)b * K_ * M_;
    for (int p = tid; p < K_ * M_; p += THREADS) {
        float s = 0.0f;
#pragma unroll
        for (int q = 0; q < 8; ++q) s += red[q * K_ * M_ + p];
        atomicAdd(&Gb[p], s);
    }
}

// ---------------- kernel 3: epilogue ----------------
__global__ void pml_epilogue_kernel(const float* __restrict__ G,
                                    const float* __restrict__ theta,
                                    float* __restrict__ out) {
    int b = blockIdx.x;
    int lane = threadIdx.x;
    if (lane >= K_) return;
    const float* Gb = G + (size_t)b * K_ * M_;

    float S[M_];
#pragma unroll
    for (int m = 0; m < M_; ++m)
        S[m] = theta[lane * M_ + m] * Gb[lane * M_ + m];

    // inclusive prefix sum over k (lanes 0..31)
#pragma unroll
    for (int m = 0; m < M_; ++m) {
        float v = S[m];
#pragma unroll
        for (int off = 1; off < K_; off <<= 1) {
            float up = __shfl_up(v, off, 32);
            if (lane >= off) v += up;
        }
        S[m] = v;
    }

    float sn2 = 0.0f;
#pragma unroll
    for (int m = 0; m < M_; ++m) sn2 = fmaf(S[m], S[m], sn2);
    float Sn = sqrtf(sn2 + EPS);
    float r = tanhf(Sn) / Sn;

    float xd[M_];
    float xdn2 = 0.0f;
#pragma unroll
    for (int m = 0; m < M_; ++m) { xd[m] = r * S[m]; xdn2 = fmaf(xd[m], xd[m], xdn2); }
    float scale = 2.0f / fmaxf(1.0f - xdn2, 1e-7f);

#pragma unroll
    for (int m = 0; m < M_; ++m)
        out[(size_t)b * (K_ * M_) + lane * M_ + m] = scale * xd[m];
}

extern "C" void kernel_launch(void* const* d_in, const int* in_sizes, int n_in,
                              void* d_out, int out_size, void* d_ws, size_t ws_size,
                              hipStream_t stream) {
    const float* dgm     = (const float*)d_in[0];   // (B, N, 17)
    const float* theta   = (const float*)d_in[1];   // (K, M)
    const float* class_w = (const float*)d_in[2];   // (2,)
    float* out = (float*)d_out;                     // (B, K*M) f32

    float*    G    = (float*)d_ws;                                  // B*K*M floats
    unsigned* finv = (unsigned*)((char*)d_ws + (size_t)B_ * K_ * M_ * sizeof(float));

    hipMemsetAsync(G, 0, (size_t)B_ * K_ * M_ * sizeof(float), stream);
    hipMemsetAsync(finv, 0xFF, (size_t)B_ * sizeof(unsigned), stream);

    scan_valid_kernel<<<(B_ * N_) / 256, 256, 0, stream>>>(dgm, finv);

    dim3 grid(CHUNKS, B_);
    pml_main_kernel<<<grid, THREADS, 0, stream>>>(dgm, theta, class_w, finv, G);

    pml_epilogue_kernel<<<B_, 64, 0, stream>>>(G, theta, out);
}

// Round 2
// 79.030 us; speedup vs baseline: 2.3816x; 2.3816x over previous
//
#include <hip/hip_runtime.h>
#include <math.h>

#define B_ 32
#define N_ 2048
#define M_ 16
#define K_ 32
#define EPS 1e-12f

constexpr int CHUNKS = 16;
constexpr int NC = N_ / CHUNKS;   // 128 rows per block
constexpr int THREADS = 256;      // 8 n-groups x 32 k
constexpr int SCAN_BLOCKS_PER_B = N_ / 256;  // 8

// ---------------- kernel 1: per-block first-invalid partials + zero G ----------------
// finv_part[blk] = min global n of an invalid row within this block's 256 rows,
// or 0xFFFFFFFF if none. No global atomics, no memset dependency.
__global__ __launch_bounds__(256) void scan_valid_kernel(
    const float* __restrict__ dgm, unsigned* __restrict__ finv_part,
    float* __restrict__ G)
{
    const int gid = blockIdx.x * 256 + threadIdx.x;
    // fold G zero-init into this kernel (grid has 65536 threads, G has 16384)
    if (gid < B_ * K_ * M_) G[gid] = 0.0f;

    const float* row = dgm + (size_t)gid * (M_ + 1);
    float v[M_ + 1];
#pragma unroll
    for (int j = 0; j < M_ + 1; ++j) v[j] = row[j];
    bool any_nz = false;
#pragma unroll
    for (int j = 0; j < M_ + 1; ++j) any_nz |= (v[j] != 0.0f);
    const bool ok = ((int)v[0] <= 1) && any_nz;

    // wave-level: lowest thread index with !ok
    unsigned long long bal = __ballot(!ok);
    const int lane = threadIdx.x & 63;
    const int wv   = threadIdx.x >> 6;
    __shared__ unsigned wmin[4];
    if (lane == 0)
        wmin[wv] = bal ? (unsigned)(wv * 64 + (__ffsll((long long)bal) - 1))
                       : 0xFFFFFFFFu;
    __syncthreads();
    if (threadIdx.x == 0) {
        unsigned mn = min(min(wmin[0], wmin[1]), min(wmin[2], wmin[3]));
        unsigned base_n = (unsigned)((blockIdx.x & (SCAN_BLOCKS_PER_B - 1)) * 256);
        finv_part[blockIdx.x] = (mn == 0xFFFFFFFFu) ? 0xFFFFFFFFu : base_n + mn;
    }
}

// ---------------- kernel 2: main accumulation ----------------
// G[b,k,m] = sum_n w[b,n] * coef[b,n,k] * y[b,n,m]
__global__ __launch_bounds__(THREADS) void pml_main_kernel(
    const float* __restrict__ dgm, const float* __restrict__ theta,
    const float* __restrict__ class_w, const unsigned* __restrict__ finv_part,
    float* __restrict__ G)
{
    __shared__ __align__(16) float y_lds[NC * M_];   // 8 KB
    __shared__ float hom_lds[NC];
    __shared__ float w_lds[NC];
    __shared__ float red[8 * K_ * M_];               // 16 KB

    const int b  = blockIdx.y;
    const int n0 = blockIdx.x * NC;

    // fi = min of this batch's 8 per-block partials (uniform, L2-cached)
    unsigned fi = 0xFFFFFFFFu;
#pragma unroll
    for (int q = 0; q < SCAN_BLOCKS_PER_B; ++q)
        fi = min(fi, finv_part[b * SCAN_BLOCKS_PER_B + q]);

    if ((unsigned)n0 >= fi) return;   // whole chunk invalid -> contributes 0

    const int tid = threadIdx.x;

    // stage dgm chunk into LDS, splitting hom / y
    const float* src = dgm + ((size_t)b * N_ + n0) * (M_ + 1);
    for (int i = tid; i < NC * (M_ + 1); i += THREADS) {
        float v = src[i];
        int nl = i / (M_ + 1);
        int j  = i - nl * (M_ + 1);
        if (j == 0) hom_lds[nl] = v;
        else        y_lds[nl * M_ + (j - 1)] = v;
    }
    __syncthreads();

    const float cw0 = class_w[0], cw1 = class_w[1];
    for (int nl = tid; nl < NC; nl += THREADS) {
        unsigned n = (unsigned)(n0 + nl);
        float w = 0.0f;
        if (n < fi) {
            int h = (int)hom_lds[nl];
            h = min(max(h, 0), 1);
            w = h ? cw1 : cw0;
        }
        w_lds[nl] = w;
    }
    __syncthreads();

    const int k   = tid & (K_ - 1);
    const int grp = tid >> 5;         // 0..7

    float t2[M_];
#pragma unroll
    for (int m = 0; m < M_; ++m) { float t = theta[k * M_ + m]; t2[m] = t * t; }

    float g[M_];
#pragma unroll
    for (int m = 0; m < M_; ++m) g[m] = 0.0f;

    const int nl_end = (int)min((unsigned)NC, fi - (unsigned)n0);

    for (int nl = grp; nl < nl_end; nl += 8) {
        float w = w_lds[nl];
        const float4* yv = (const float4*)(y_lds + nl * M_);
        float4 v0 = yv[0], v1 = yv[1], v2 = yv[2], v3 = yv[3];
        float y[M_] = { v0.x, v0.y, v0.z, v0.w,  v1.x, v1.y, v1.z, v1.w,
                        v2.x, v2.y, v2.z, v2.w,  v3.x, v3.y, v3.z, v3.w };
        float s = 0.0f;
#pragma unroll
        for (int m = 0; m < M_; ++m) s = fmaf(y[m] * y[m], t2[m], s);
        // d = 1 + sqrt(1 + un^2), un^2 = s + EPS
        float d  = 1.0f + sqrtf(1.0f + s + EPS);
        float xn = sqrtf(s / (d * d) + EPS);
        float xc = fminf(xn, 1.0f - 1e-5f);
        float coef = atanhf(xc) / (xn * d);
        float wc = w * coef;
#pragma unroll
        for (int m = 0; m < M_; ++m) g[m] = fmaf(wc, y[m], g[m]);
    }

    // block reduction over the 8 n-groups
    float* myred = red + (grp * K_ + k) * M_;
#pragma unroll
    for (int m = 0; m < M_; ++m) myred[m] = g[m];
    __syncthreads();

    float* Gb = G + (size_t)b * K_ * M_;
    for (int p = tid; p < K_ * M_; p += THREADS) {
        float s = 0.0f;
#pragma unroll
        for (int q = 0; q < 8; ++q) s += red[q * K_ * M_ + p];
        atomicAdd(&Gb[p], s);
    }
}

// ---------------- kernel 3: epilogue ----------------
__global__ void pml_epilogue_kernel(const float* __restrict__ G,
                                    const float* __restrict__ theta,
                                    float* __restrict__ out) {
    int b = blockIdx.x;
    int lane = threadIdx.x;
    if (lane >= K_) return;
    const float* Gb = G + (size_t)b * K_ * M_;

    float S[M_];
#pragma unroll
    for (int m = 0; m < M_; ++m)
        S[m] = theta[lane * M_ + m] * Gb[lane * M_ + m];

    // inclusive prefix sum over k (lanes 0..31)
#pragma unroll
    for (int m = 0; m < M_; ++m) {
        float v = S[m];
#pragma unroll
        for (int off = 1; off < K_; off <<= 1) {
            float up = __shfl_up(v, off, 32);
            if (lane >= off) v += up;
        }
        S[m] = v;
    }

    float sn2 = 0.0f;
#pragma unroll
    for (int m = 0; m < M_; ++m) sn2 = fmaf(S[m], S[m], sn2);
    float Sn = sqrtf(sn2 + EPS);
    float r = tanhf(Sn) / Sn;

    float xd[M_];
    float xdn2 = 0.0f;
#pragma unroll
    for (int m = 0; m < M_; ++m) { xd[m] = r * S[m]; xdn2 = fmaf(xd[m], xd[m], xdn2); }
    float scale = 2.0f / fmaxf(1.0f - xdn2, 1e-7f);

#pragma unroll
    for (int m = 0; m < M_; ++m)
        out[(size_t)b * (K_ * M_) + lane * M_ + m] = scale * xd[m];
}

extern "C" void kernel_launch(void* const* d_in, const int* in_sizes, int n_in,
                              void* d_out, int out_size, void* d_ws, size_t ws_size,
                              hipStream_t stream) {
    const float* dgm     = (const float*)d_in[0];   // (B, N, 17)
    const float* theta   = (const float*)d_in[1];   // (K, M)
    const float* class_w = (const float*)d_in[2];   // (2,)
    float* out = (float*)d_out;                     // (B, K*M) f32

    float*    G         = (float*)d_ws;             // B*K*M floats (zeroed by scan kernel)
    unsigned* finv_part = (unsigned*)((char*)d_ws + (size_t)B_ * K_ * M_ * sizeof(float));
    // finv_part: B_*8 entries, every slot written by scan kernel (no init needed)

    scan_valid_kernel<<<(B_ * N_) / 256, 256, 0, stream>>>(dgm, finv_part, G);

    dim3 grid(CHUNKS, B_);
    pml_main_kernel<<<grid, THREADS, 0, stream>>>(dgm, theta, class_w, finv_part, G);

    pml_epilogue_kernel<<<B_, 64, 0, stream>>>(G, theta, out);
}